// Round 5
// baseline (278.996 us; speedup 1.0000x reference)
//
#include <hip/hip_runtime.h>
#include <hip/hip_bf16.h>

#define B_ 64
#define S_ 1024
#define H_ 256
#define E_ 256

#define EG_ 32          // e-columns per k2 block
#define LDSB_ST 264     // bf16 stride for B panel (256 data + 8 pad)
#define CH_ 128         // rows per s-chunk (8 waves x 16)
#define NCH_ 8          // s-chunks per batch

typedef __attribute__((ext_vector_type(8))) __bf16 bf16x8;
typedef __attribute__((ext_vector_type(4))) __bf16 bf16x4;
typedef __attribute__((ext_vector_type(4))) float f32x4;

// ---- k0: w[m] = exp(alpha[m,:].Wa + ba) * mask[m] for all 65536 rows,
//          plus Wb fp32->bf16 convert on the first 64 blocks. No sync, no atomics.
__global__ __launch_bounds__(256) void k0_prep(
        const float* __restrict__ alpha, const float* __restrict__ mask,
        const float* __restrict__ Wa,    const float* __restrict__ ba,
        const float* __restrict__ Wb,    __bf16* __restrict__ WbBf,
        float* __restrict__ w) {
    const int tid = threadIdx.x, blk = blockIdx.x;
    if (blk < 64) {   // 64 blocks x 256 thr x 1 float4 == 65536 Wb floats
        int i = blk * 256 + tid;
        float4 v = ((const float4*)Wb)[i];
        bf16x4 bv;
        bv[0] = (__bf16)v.x; bv[1] = (__bf16)v.y;
        bv[2] = (__bf16)v.z; bv[3] = (__bf16)v.w;
        ((bf16x4*)WbBf)[i] = bv;
    }
    // phase W: 4 lanes per row, 64 rows per block
    const int pr = tid >> 2, pc = tid & 3;
    const int m = blk * 64 + pr;
    const float4* ar = (const float4*)(alpha + (size_t)m * H_ + pc * 64);
    const float4* wr = (const float4*)(Wa + pc * 64);
    float p = 0.f;
    #pragma unroll
    for (int i = 0; i < 16; ++i) {
        float4 a = ar[i], v = wr[i];
        p += a.x * v.x + a.y * v.y + a.z * v.z + a.w * v.w;
    }
    p += __shfl_xor(p, 1, 64);
    p += __shfl_xor(p, 2, 64);
    if (pc == 0) w[m] = __expf(p + ba[0]) * mask[m];
}

// ---- k2: block = (batch b, 32 e-columns). Owns ALL s for those columns:
//   B-panel LDS-stationary (loaded once); loop s-chunks DESCENDING, carrying
//   run[e] (suffix of later chunks) in LDS. Zero inter-block communication.
// 512 thr = 8 waves; wave wv owns rows [c*128 + wv*16, +16) each chunk.
__global__ __launch_bounds__(512, 4) void k2_main(
        const float* __restrict__ beta, const float* __restrict__ embed,
        const __bf16* __restrict__ WbBf, const float* __restrict__ bb,
        const float* __restrict__ w, float* __restrict__ t) {
    __shared__ __bf16 ldsB[EG_ * LDSB_ST];   // 16.9 KB, stationary B panel
    __shared__ float wsLds[S_];              // 4 KB   w[b, :]
    __shared__ float ivLds[S_];              // 4 KB   1/(w-suffix + eps)
    __shared__ float red[8 * EG_];           // per-wave column totals
    __shared__ float run[EG_];               // carry: totals of chunks > c
    __shared__ float wsum[4];

    const int tid = threadIdx.x;
    const int wv = tid >> 6, lane = tid & 63;
    const int l15 = lane & 15, q = lane >> 4;
    const int blk = blockIdx.x;
    // XCD co-location: all 8 e-groups of a batch land on one XCD (blk%8 fixed)
    const int b  = (blk & 7) * 8 + (blk >> 6);   // 0..63
    const int eg = (blk >> 3) & 7;               // 0..7

    // ---- stage w + B-panel + init carry ----
    if (tid < 256)
        *(float4*)(wsLds + tid * 4) = *(const float4*)(w + b * S_ + tid * 4);
    {
        const int e = tid >> 4, ks = (tid & 15) * 16;
        const __bf16* src = WbBf + (size_t)(eg * EG_ + e) * H_ + ks;
        *(bf16x8*)(ldsB + e * LDSB_ST + ks)     = *(const bf16x8*)(src);
        *(bf16x8*)(ldsB + e * LDSB_ST + ks + 8) = *(const bf16x8*)(src + 8);
    }
    if (tid < EG_) run[tid] = 0.f;
    __syncthreads();

    // ---- in-LDS suffix scan of w -> ivLds (256 threads, 4 elems each) ----
    {
        float w0 = 0, w1 = 0, w2 = 0, w3 = 0, tot = 0, suf = 0;
        const int sl = tid & 63, sw = tid >> 6;
        if (tid < 256) {
            w0 = wsLds[tid * 4];     w1 = wsLds[tid * 4 + 1];
            w2 = wsLds[tid * 4 + 2]; w3 = wsLds[tid * 4 + 3];
            tot = w0 + w1 + w2 + w3;
            suf = tot;
            #pragma unroll
            for (int off = 1; off < 64; off <<= 1) {
                float o = __shfl_down(suf, off, 64);
                if (sl + off < 64) suf += o;
            }
            if (sl == 0) wsum[sw] = suf;   // wave-inclusive suffix at lane0 = total
        }
        __syncthreads();
        if (tid < 256) {
            float waveOff = 0.f;
            for (int j = sw + 1; j < 4; ++j) waveOff += wsum[j];
            float after = (suf - tot) + waveOff;   // exclusive suffix beyond thread
            float s3 = w3 + after, s2 = w2 + s3, s1 = w1 + s2, s0 = w0 + s1;
            ivLds[tid * 4]     = 1.f / (s0 + 1e-10f);
            ivLds[tid * 4 + 1] = 1.f / (s1 + 1e-10f);
            ivLds[tid * 4 + 2] = 1.f / (s2 + 1e-10f);
            ivLds[tid * 4 + 3] = 1.f / (s3 + 1e-10f);
        }
        __syncthreads();
    }

    const float bb0 = bb[eg * EG_ + l15];
    const float bb1 = bb[eg * EG_ + 16 + l15];

    // ---- s-chunks, descending (causal suffix) ----
    for (int c = NCH_ - 1; c >= 0; --c) {
        const int rbase = c * CH_ + wv * 16;
        const float* Ar = beta + (size_t)(b * S_ + rbase + l15) * H_ + q * 8;

        f32x4 acc0 = {0.f, 0.f, 0.f, 0.f}, acc1 = {0.f, 0.f, 0.f, 0.f};
        #pragma unroll
        for (int kc = 0; kc < 8; ++kc) {
            float4 a0 = *(const float4*)(Ar + kc * 32);
            float4 a1 = *(const float4*)(Ar + kc * 32 + 4);
            bf16x8 af;
            af[0] = (__bf16)a0.x; af[1] = (__bf16)a0.y;
            af[2] = (__bf16)a0.z; af[3] = (__bf16)a0.w;
            af[4] = (__bf16)a1.x; af[5] = (__bf16)a1.y;
            af[6] = (__bf16)a1.z; af[7] = (__bf16)a1.w;
            bf16x8 bf0 = *(const bf16x8*)(ldsB + l15 * LDSB_ST + kc * 32 + q * 8);
            bf16x8 bf1 = *(const bf16x8*)(ldsB + (16 + l15) * LDSB_ST + kc * 32 + q * 8);
            acc0 = __builtin_amdgcn_mfma_f32_16x16x32_bf16(af, bf0, acc0, 0, 0, 0);
            acc1 = __builtin_amdgcn_mfma_f32_16x16x32_bf16(af, bf1, acc1, 0, 0, 0);
        }

        // epilogue: tanh * w * embed, wave-local 16-row suffix. C layout:
        // col(e)=lane&15, row(s)=q*4+r.
        float sv0[4], sv1[4];
        {
            const int eG = eg * EG_ + l15;
            float tv[4];
            #pragma unroll
            for (int r = 0; r < 4; ++r) {
                const int m = c * CH_ + wv * 16 + q * 4 + r;
                float x = acc0[r] + bb0;
                x = fminf(fmaxf(x, -15.f), 15.f);
                float ex = __expf(2.f * x);
                float th = (ex - 1.f) / (ex + 1.f);
                tv[r] = wsLds[m] * th * embed[(size_t)(b * S_ + m) * E_ + eG];
            }
            float s3 = tv[3], s2 = tv[2] + s3, s1 = tv[1] + s2, s0 = tv[0] + s1;
            float g = s0;
            float g1 = __shfl_down(g, 16, 64);
            float g2 = __shfl_down(g, 32, 64);
            float g3 = __shfl_down(g, 48, 64);
            float addG = (q < 3 ? g1 : 0.f) + (q < 2 ? g2 : 0.f) + (q < 1 ? g3 : 0.f);
            if (q == 0) red[wv * EG_ + l15] = g + addG;
            sv0[0] = s0 + addG; sv0[1] = s1 + addG;
            sv0[2] = s2 + addG; sv0[3] = s3 + addG;
        }
        {
            const int eG = eg * EG_ + 16 + l15;
            float tv[4];
            #pragma unroll
            for (int r = 0; r < 4; ++r) {
                const int m = c * CH_ + wv * 16 + q * 4 + r;
                float x = acc1[r] + bb1;
                x = fminf(fmaxf(x, -15.f), 15.f);
                float ex = __expf(2.f * x);
                float th = (ex - 1.f) / (ex + 1.f);
                tv[r] = wsLds[m] * th * embed[(size_t)(b * S_ + m) * E_ + eG];
            }
            float s3 = tv[3], s2 = tv[2] + s3, s1 = tv[1] + s2, s0 = tv[0] + s1;
            float g = s0;
            float g1 = __shfl_down(g, 16, 64);
            float g2 = __shfl_down(g, 32, 64);
            float g3 = __shfl_down(g, 48, 64);
            float addG = (q < 3 ? g1 : 0.f) + (q < 2 ? g2 : 0.f) + (q < 1 ? g3 : 0.f);
            if (q == 0) red[wv * EG_ + 16 + l15] = g + addG;
            sv1[0] = s0 + addG; sv1[1] = s1 + addG;
            sv1[2] = s2 + addG; sv1[3] = s3 + addG;
        }
        __syncthreads();   // red published

        // cross-wave (later waves) + cross-chunk carry; final store
        float nr0 = 0.f, nr1 = 0.f;
        {
            const int eG = eg * EG_ + l15;
            const float rn = run[l15];
            float later = rn, tot = 0.f;
            #pragma unroll
            for (int w2 = 0; w2 < 8; ++w2) {
                float v = red[w2 * EG_ + l15];
                tot += v;
                if (w2 > wv) later += v;
            }
            nr0 = rn + tot;
            #pragma unroll
            for (int r = 0; r < 4; ++r) {
                const int m = c * CH_ + wv * 16 + q * 4 + r;
                t[(size_t)(b * S_ + m) * E_ + eG] = (sv0[r] + later) * ivLds[m];
            }
        }
        {
            const int eG = eg * EG_ + 16 + l15;
            const float rn = run[16 + l15];
            float later = rn, tot = 0.f;
            #pragma unroll
            for (int w2 = 0; w2 < 8; ++w2) {
                float v = red[w2 * EG_ + 16 + l15];
                tot += v;
                if (w2 > wv) later += v;
            }
            nr1 = rn + tot;
            #pragma unroll
            for (int r = 0; r < 4; ++r) {
                const int m = c * CH_ + wv * 16 + q * 4 + r;
                t[(size_t)(b * S_ + m) * E_ + eG] = (sv1[r] + later) * ivLds[m];
            }
        }
        __syncthreads();   // all reads of red/run done
        if (wv == 0 && q == 0) {       // 16 lanes x 2 tiles cover run[0..32)
            run[l15] = nr0;
            run[16 + l15] = nr1;
        }
        // next chunk's pre-store barrier orders this write before its readers
    }
}

extern "C" void kernel_launch(void* const* d_in, const int* in_sizes, int n_in,
                              void* d_out, int out_size, void* d_ws, size_t ws_size,
                              hipStream_t stream) {
    const float* alpha = (const float*)d_in[0];
    const float* beta  = (const float*)d_in[1];
    const float* embed = (const float*)d_in[2];
    const float* mask  = (const float*)d_in[3];
    const float* Wb    = (const float*)d_in[4];
    const float* bbp   = (const float*)d_in[5];
    const float* Wa    = (const float*)d_in[6];
    const float* bap   = (const float*)d_in[7];

    float* t = (float*)d_out;

    char* ws = (char*)d_ws;
    float*  w    = (float*)ws;                    // 256 KB
    __bf16* WbBf = (__bf16*)(ws + (256 << 10));   // 128 KB

    k0_prep<<<B_ * S_ / 64, 256, 0, stream>>>(alpha, mask, Wa, bap, Wb, WbBf, w);
    k2_main<<<B_ * (E_ / EG_), 512, 0, stream>>>(beta, embed, WbBf, bbp, w, t);
}